// Round 10
// baseline (264.040 us; speedup 1.0000x reference)
//
#include <hip/hip_runtime.h>

typedef __attribute__((ext_vector_type(8))) short bf16x8;
typedef __attribute__((ext_vector_type(4))) float f32x4;

constexpr int kB = 2, kN = 4096, kC = 512, kNH = 8, kHD = 64;
constexpr int kBN = kB * kN;                 // 8192
constexpr int kWElems = 262144;              // 512*512
constexpr int kWAll = 6 * kWElems;           // 6 weight matrices
constexpr int kWExtra = 3584;                // dwk(1536) + dwb(512) + dwkT(1536)
constexpr float kQScale = 0.1803368801f;     // (1/8) * log2(e)

__device__ __forceinline__ short f2bf(float f) {
  union { float f; unsigned u; } v; v.f = f;
  unsigned r = v.u + 0x7fffu + ((v.u >> 16) & 1u);
  return (short)(r >> 16);
}
__device__ __forceinline__ float bf2f(short s) {
  union { unsigned u; float f; } v; v.u = ((unsigned)(unsigned short)s) << 16;
  return v.f;
}
__device__ __forceinline__ float exp2_(float x) {
#if __has_builtin(__builtin_amdgcn_exp2f)
  return __builtin_amdgcn_exp2f(x);
#else
  return exp2f(x);
#endif
}
// pack two f32 -> two bf16 (round-half-up) in one dword via v_perm
__device__ __forceinline__ unsigned pk2bf(float a, float b) {
  union { float f; unsigned u; } ua, ub; ua.f = a; ub.f = b;
#if __has_builtin(__builtin_amdgcn_perm)
  return __builtin_amdgcn_perm(ub.u + 0x8000u, ua.u + 0x8000u, 0x07060302u);
#else
  return ((ua.u + 0x8000u) >> 16) | (((ub.u + 0x8000u) >> 16) << 16);
#endif
}

__device__ __forceinline__ bf16x8 ld8(const short* p) { return *(const bf16x8*)p; }
__device__ __forceinline__ bf16x8 ld8(const float* p) {
  float4 a = *(const float4*)p;
  float4 b = *(const float4*)(p + 4);
  bf16x8 r;
  r[0] = f2bf(a.x); r[1] = f2bf(a.y); r[2] = f2bf(a.z); r[3] = f2bf(a.w);
  r[4] = f2bf(b.x); r[5] = f2bf(b.y); r[6] = f2bf(b.z); r[7] = f2bf(b.w);
  return r;
}
__device__ __forceinline__ void stf(short* p, float v) { *p = f2bf(v); }
__device__ __forceinline__ void stf(float* p, float v) { *p = v; }

// async 16B global->LDS (LDS dest wave-uniform base + 16*lane).
__device__ __forceinline__ void gload_lds16(const void* g, void* l) {
  __builtin_amdgcn_global_load_lds(
      (const __attribute__((address_space(1))) void*)g,
      (__attribute__((address_space(3))) void*)l, 16, 0, 0);
}

// K0: classify input dtype on-device.
__global__ void detect_dtype(const unsigned* __restrict__ x, int* __restrict__ flag) {
  const int lane = threadIdx.x & 63;
  unsigned w = x[lane];
  int e = (int)((w >> 7) & 0xffu);
  bool bf = (e >= 100 && e <= 140);
  unsigned long long m = __ballot(bf);
  if (lane == 0) *flag = (__popcll(m) >= 32) ? 1 : 0;
}

// K0b: weights AND x -> bf16 in one launch.
constexpr int kW8 = kWAll / 8;        // 196608
constexpr int kX8 = kBN * kC / 8;     // 524288
__global__ __launch_bounds__(256) void convert_all(
    const void* Wq, const void* Wk, const void* Wv, const void* Wc,
    const void* Wa, const void* Wco, const void* dwk, const void* dwb,
    const void* x, const int* __restrict__ flag, short* __restrict__ dst,
    short* __restrict__ xb) {
  const int gtid = blockIdx.x * 256 + threadIdx.x;
  const bool bf = (*flag != 0);
  if (gtid < kW8) {
    const int e = gtid * 8;
    const int t = e >> 18, off = e & (kWElems - 1);
    const void* src = (t == 0) ? Wq : (t == 1) ? Wk : (t == 2) ? Wv
                    : (t == 3) ? Wc : (t == 4) ? Wa : Wco;
    bf16x8 v = bf ? ld8((const short*)src + off) : ld8((const float*)src + off);
    *(bf16x8*)(dst + e) = v;
  } else if (gtid < kW8 + kWExtra) {
    const int eoff = gtid - kW8;
    if (eoff < 1536) {
      dst[kWAll + eoff] = bf ? ((const short*)dwk)[eoff]
                             : f2bf(((const float*)dwk)[eoff]);
    } else if (eoff < 2048) {
      const int i = eoff - 1536;
      dst[kWAll + 1536 + i] = bf ? ((const short*)dwb)[i]
                                 : f2bf(((const float*)dwb)[i]);
    } else {
      const int t2 = eoff - 2048;
      const int tap = t2 >> 9, c = t2 & 511;
      dst[kWAll + 2048 + t2] = bf ? ((const short*)dwk)[c * 3 + tap]
                                  : f2bf(((const float*)dwk)[c * 3 + tap]);
    }
  } else if (gtid < kW8 + kWExtra + kX8) {
    const int e = (gtid - kW8 - kWExtra) * 8;
    bf16x8 v = bf ? ld8((const short*)x + e) : ld8((const float*)x + e);
    *(bf16x8*)(xb + e) = v;
  }
}

// K1: fused input projection GEMM [8192x512] x [2048x512]^T (R9, control).
__global__ __launch_bounds__(256, 3) void proj_gemm(
    const short* __restrict__ xb, const short* __restrict__ wb,
    short* __restrict__ q, short* __restrict__ k, short* __restrict__ vT,
    short* __restrict__ ci) {
  __shared__ __align__(16) short As[128 * 64];
  __shared__ __align__(16) short Bs[128 * 64];
  const int t = threadIdx.x;
  const int wave = t >> 6, lane = t & 63;
  const int row = lane & 15, quad = lane >> 4;
  const int bn = blockIdx.x & 15;
  const int bm = blockIdx.x >> 4;
  const int m0 = bm * 128, n0 = bn * 128;
  const int wm = wave & 1, wn = wave >> 1;
  const int lrow = lane >> 3, lch = lane & 7;

  f32x4 acc[4][4];
#pragma unroll
  for (int mi = 0; mi < 4; ++mi)
#pragma unroll
    for (int ni = 0; ni < 4; ++ni)
#pragma unroll
      for (int r = 0; r < 4; ++r) acc[mi][ni][r] = 0.0f;

  for (int k0 = 0; k0 < kC; k0 += 64) {
#pragma unroll
    for (int p = 0; p < 4; ++p) {
      const int m = wave * 32 + p * 8 + lrow;
      const int kch = lch ^ (m & 7);
      gload_lds16(xb + (size_t)(m0 + m) * kC + k0 + kch * 8,
                  &As[(wave * 32 + p * 8) * 64]);
      gload_lds16(wb + (size_t)(n0 + m) * kC + k0 + kch * 8,
                  &Bs[(wave * 32 + p * 8) * 64]);
    }
    __syncthreads();

#pragma unroll
    for (int kk2 = 0; kk2 < 2; ++kk2) {
      bf16x8 af[4], bfr[4];
#pragma unroll
      for (int mi = 0; mi < 4; ++mi) {
        const int m = wm * 64 + mi * 16 + row;
        const int ch = (kk2 * 4 + quad) ^ (m & 7);
        af[mi] = *(const bf16x8*)(&As[m * 64 + ch * 8]);
      }
#pragma unroll
      for (int ni = 0; ni < 4; ++ni) {
        const int n = wn * 64 + ni * 16 + row;
        const int ch = (kk2 * 4 + quad) ^ (n & 7);
        bfr[ni] = *(const bf16x8*)(&Bs[n * 64 + ch * 8]);
      }
#pragma unroll
      for (int mi = 0; mi < 4; ++mi)
#pragma unroll
        for (int ni = 0; ni < 4; ++ni)
          acc[mi][ni] = __builtin_amdgcn_mfma_f32_16x16x32_bf16(
              af[mi], bfr[ni], acc[mi][ni], 0, 0, 0);
    }
    __syncthreads();
  }

  const int gc0 = n0 + wn * 64;
  const int mat = gc0 >> 9;
  const float scale = (mat == 0) ? kQScale : 1.0f;
#pragma unroll
  for (int mi = 0; mi < 4; ++mi) {
#pragma unroll
    for (int ni = 0; ni < 4; ++ni) {
#pragma unroll
      for (int r = 0; r < 4; ++r) {
        const int gm = m0 + wm * 64 + mi * 16 + quad * 4 + r;
        const int c_ = ((gc0 + ni * 16) & 511) + row;
        const int b_ = gm >> 12;
        const int n_ = gm & (kN - 1);
        const short bv = f2bf(acc[mi][ni][r] * scale);
        if (mat == 3) {
          ci[(b_ * kN + n_) * kC + c_] = bv;
        } else {
          const int h = c_ >> 6, d = c_ & 63;
          const int bh = b_ * kNH + h;
          if (mat == 0)      q[(bh * kN + n_) * kHD + d] = bv;
          else if (mat == 1) k[(bh * kN + n_) * kHD + d] = bv;
          else               vT[(bh * kHD + d) * kN + n_] = bv;
        }
      }
    }
  }
}

// K2: depthwise conv, vectorized bf16x8.
__global__ __launch_bounds__(256) void dwconv(
    const short* __restrict__ ci, const short* __restrict__ wb,
    short* __restrict__ cb) {
  const int e0 = (blockIdx.x * 256 + threadIdx.x) * 8;
  const int c0 = e0 & (kC - 1);
  const int bn = e0 >> 9;
  const int n_ = bn & (kN - 1);
  bf16x8 xc = ld8(ci + e0);
  bf16x8 xm, xp;
  if (n_ > 0) xm = ld8(ci + e0 - kC);
  else
#pragma unroll
    for (int i = 0; i < 8; ++i) xm[i] = 0;
  if (n_ < kN - 1) xp = ld8(ci + e0 + kC);
  else
#pragma unroll
    for (int i = 0; i < 8; ++i) xp[i] = 0;
  bf16x8 w0 = ld8(wb + kWAll + 2048 + c0);
  bf16x8 w1 = ld8(wb + kWAll + 2048 + 512 + c0);
  bf16x8 w2 = ld8(wb + kWAll + 2048 + 1024 + c0);
  bf16x8 bi = ld8(wb + kWAll + 1536 + c0);
  bf16x8 o;
#pragma unroll
  for (int i = 0; i < 8; ++i) {
    float a = bf2f(bi[i]) + bf2f(xm[i]) * bf2f(w0[i]) +
              bf2f(xc[i]) * bf2f(w1[i]) + bf2f(xp[i]) * bf2f(w2[i]);
    o[i] = f2bf(a);
  }
  *(bf16x8*)(cb + e0) = o;
}

// ---------------------------------------------------------------------------
// K3: flash attention v6 — 64 q-rows/wave, optional split-K(2).
//  - Fixed-ref softmax makes split-K a PURE SUM: O=O0+O1, l=l0+l1.
//  - K staged via global_load_lds DMA, XOR-source-swizzled, unpadded [64][64]
//    (no VGPR round-trip; bank-uniform reads at slot ch^(m&7)).
//  - V register-staged as 4x b64 into permuted [64][72] layout (R9).
//  - P^T in registers (R8); one barrier per kt.
//  - S==2: writes bf16 partial O ([B][N][C] layout) + per-row l.
//    S==1: normalizes inline (fallback when ws too small for partials).
// ---------------------------------------------------------------------------
__global__ __launch_bounds__(256, 2) void attn_flash(
    const short* __restrict__ q, const short* __restrict__ k,
    const short* __restrict__ vT, short* __restrict__ pO0,
    short* __restrict__ pO1, float* __restrict__ pl, int S) {
  __shared__ __align__(16) short Kb[2][64 * 64];   // 16 KB, XOR-swizzled
  __shared__ __align__(16) short Vb[2][64 * 72];   // 18 KB, permuted
  const int t = threadIdx.x;
  const int wave = t >> 6, lane = t & 63;
  const int row = lane & 15, quad = lane >> 4;

  const int slot = blockIdx.x & 7;
  const int inner = blockIdx.x >> 3;
  const int bh = slot * 2 + (inner & 1);
  const int ks = (S == 2) ? ((inner >> 1) & 1) : 0;
  const int qt = (S == 2) ? (inner >> 2) : (inner >> 1);
  const int q0 = qt * 256 + wave * 64;
  const int ktN = (S == 2) ? 32 : 64;
  const int ktBase = ks * ktN;

  const short* qbase = q + (bh * kN + q0) * kHD;
  const short* kbase = k + bh * kN * kHD;
  const short* vbase = vT + bh * kHD * kN;

  // Q fragments: 4 groups of 16 q-rows.
  bf16x8 qb[4][2];
#pragma unroll
  for (int g = 0; g < 4; ++g) {
    qb[g][0] = *(const bf16x8*)(qbase + (g * 16 + row) * kHD + quad * 8);
    qb[g][1] = *(const bf16x8*)(qbase + (g * 16 + row) * kHD + 32 + quad * 8);
  }

  f32x4 o[4][4];   // o[g][jd][r] = O^T[jd*16+quad*4+r][q=g*16+row]
#pragma unroll
  for (int g = 0; g < 4; ++g)
#pragma unroll
    for (int j = 0; j < 4; ++j)
#pragma unroll
      for (int r = 0; r < 4; ++r) o[g][j][r] = 0.0f;
  float l_[4] = {0.f, 0.f, 0.f, 0.f};

  // K DMA staging: wave stages rows [wave*16, +16) of the tile.
  const int km1 = wave * 16 + (lane >> 3);
  const int km2 = km1 + 8;
  const int kc1 = ((lane & 7) ^ (km1 & 7)) * 8;
  const int kc2 = ((lane & 7) ^ (km2 & 7)) * 8;

  // V staging: thread handles chunks i0=t, i1=t+256 (row sr, chunk sc).
  const int i0 = t, i1 = t + 256;
  const int sr0 = i0 >> 3, sc0 = i0 & 7;
  const int sr1 = i1 >> 3, sc1 = i1 & 7;
  const int vd0 = (sc0 >> 2) * 32 + (sc0 & 1) * 16 + (sc0 & 2) * 2;
  const int vd1 = (sc1 >> 2) * 32 + (sc1 & 1) * 16 + (sc1 & 2) * 2;

  { // prologue: K(ktBase) DMA, V(ktBase) via regs
    gload_lds16(kbase + (ktBase * 64 + km1) * 64 + kc1, &Kb[0][(wave * 16) * 64]);
    gload_lds16(kbase + (ktBase * 64 + km2) * 64 + kc2, &Kb[0][(wave * 16 + 8) * 64]);
    const short* v0 = vbase + sr0 * kN + ktBase * 64 + sc0 * 8;
    const short* v1 = vbase + sr1 * kN + ktBase * 64 + sc1 * 8;
    *(short4*)(&Vb[0][sr0 * 72 + vd0])     = *(const short4*)v0;
    *(short4*)(&Vb[0][sr0 * 72 + vd0 + 8]) = *(const short4*)(v0 + 4);
    *(short4*)(&Vb[0][sr1 * 72 + vd1])     = *(const short4*)v1;
    *(short4*)(&Vb[0][sr1 * 72 + vd1 + 8]) = *(const short4*)(v1 + 4);
  }
  __syncthreads();

  for (int kt = ktBase; kt < ktBase + ktN; ++kt) {
    const int cur = kt & 1;
    const bool more = (kt < ktBase + ktN - 1);
    short4 vn0a, vn0b, vn1a, vn1b;
    if (more) {
      // K(kt+1) DMA straight into the other buffer (async, drains at barrier)
      gload_lds16(kbase + ((kt + 1) * 64 + km1) * 64 + kc1,
                  &Kb[1 - cur][(wave * 16) * 64]);
      gload_lds16(kbase + ((kt + 1) * 64 + km2) * 64 + kc2,
                  &Kb[1 - cur][(wave * 16 + 8) * 64]);
      const short* v0 = vbase + sr0 * kN + (kt + 1) * 64 + sc0 * 8;
      const short* v1 = vbase + sr1 * kN + (kt + 1) * 64 + sc1 * 8;
      vn0a = *(const short4*)v0; vn0b = *(const short4*)(v0 + 4);
      vn1a = *(const short4*)v1; vn1b = *(const short4*)(v1 + 4);
    }

    // ---- load K fragments once (8 b128), reused across 4 q-groups ----
    bf16x8 ka[4][2];
#pragma unroll
    for (int jk = 0; jk < 4; ++jk) {
      const int m = jk * 16 + row;
      ka[jk][0] = *(const bf16x8*)(&Kb[cur][m * 64 + (quad ^ (m & 7)) * 8]);
      ka[jk][1] = *(const bf16x8*)(&Kb[cur][m * 64 + ((quad + 4) ^ (m & 7)) * 8]);
    }

    // ---- per-group QK -> softmax -> P^T regs ----
    bf16x8 pb[4][2];
#pragma unroll
    for (int g = 0; g < 4; ++g) {
      f32x4 s[4];
#pragma unroll
      for (int jk = 0; jk < 4; ++jk)
#pragma unroll
        for (int r = 0; r < 4; ++r) s[jk][r] = 0.0f;
#pragma unroll
      for (int jk = 0; jk < 4; ++jk) {
        s[jk] = __builtin_amdgcn_mfma_f32_16x16x32_bf16(ka[jk][0], qb[g][0], s[jk], 0, 0, 0);
        s[jk] = __builtin_amdgcn_mfma_f32_16x16x32_bf16(ka[jk][1], qb[g][1], s[jk], 0, 0, 0);
      }
      float rs = 0.0f;
#pragma unroll
      for (int jk = 0; jk < 4; ++jk)
#pragma unroll
        for (int r = 0; r < 4; ++r) {
          float p = exp2_(s[jk][r]);
          s[jk][r] = p;
          rs += p;
        }
      l_[g] += rs;
#pragma unroll
      for (int c = 0; c < 2; ++c) {
        union { unsigned u[4]; bf16x8 v; } pu;
        pu.u[0] = pk2bf(s[2 * c][0], s[2 * c][1]);
        pu.u[1] = pk2bf(s[2 * c][2], s[2 * c][3]);
        pu.u[2] = pk2bf(s[2 * c + 1][0], s[2 * c + 1][1]);
        pu.u[3] = pk2bf(s[2 * c + 1][2], s[2 * c + 1][3]);
        pb[g][c] = pu.v;
      }
    }

    // ---- stage V(kt+1) into other buffer ----
    if (more) {
      *(short4*)(&Vb[1 - cur][sr0 * 72 + vd0])     = vn0a;
      *(short4*)(&Vb[1 - cur][sr0 * 72 + vd0 + 8]) = vn0b;
      *(short4*)(&Vb[1 - cur][sr1 * 72 + vd1])     = vn1a;
      *(short4*)(&Vb[1 - cur][sr1 * 72 + vd1 + 8]) = vn1b;
    }

    // ---- PV: A = b128 from permuted V, B = pb regs ----
#pragma unroll
    for (int jd = 0; jd < 4; ++jd) {
      const short* vb = &Vb[cur][(jd * 16 + row) * 72 + quad * 8];
#pragma unroll
      for (int c = 0; c < 2; ++c) {
        bf16x8 av = *(const bf16x8*)(vb + c * 32);
#pragma unroll
        for (int g = 0; g < 4; ++g)
          o[g][jd] = __builtin_amdgcn_mfma_f32_16x16x32_bf16(
              av, pb[g][c], o[g][jd], 0, 0, 0);
      }
    }
    __syncthreads();
  }

  // ---- epilogue ----
  const int b_ = bh >> 3, h = bh & 7;
  short* pO = (ks == 0) ? pO0 : pO1;
#pragma unroll
  for (int g = 0; g < 4; ++g) {
    float lt = l_[g];
    lt += __shfl_xor(lt, 16);
    lt += __shfl_xor(lt, 32);
    const int n_ = q0 + g * 16 + row;
    short* ob = pO + (b_ * kN + n_) * kC + h * kHD + quad * 4;
    const float linv = (S == 1) ? (1.0f / lt) : 1.0f;
#pragma unroll
    for (int jd = 0; jd < 4; ++jd) {
      short4 st = make_short4(f2bf(o[g][jd][0] * linv), f2bf(o[g][jd][1] * linv),
                              f2bf(o[g][jd][2] * linv), f2bf(o[g][jd][3] * linv));
      *(short4*)(ob + jd * 16) = st;
    }
    if (S == 2 && quad == 0) pl[ks * 65536 + bh * kN + n_] = lt;
  }
}

// K3b: combine split-K partials: attn = (pO0 + pO1) / (l0 + l1), in place.
__global__ __launch_bounds__(256) void attn_combine(
    short* __restrict__ pO0, const short* __restrict__ pO1,
    const float* __restrict__ pl) {
  const int i8 = (blockIdx.x * 256 + threadIdx.x) * 8;
  const int b_ = i8 >> 21;
  const int n_ = (i8 >> 9) & (kN - 1);
  const int c0 = i8 & (kC - 1);
  const int bh = b_ * kNH + (c0 >> 6);
  const float rl = 1.0f / (pl[bh * kN + n_] + pl[65536 + bh * kN + n_]);
  bf16x8 a = ld8(pO0 + i8), b = ld8(pO1 + i8);
  bf16x8 o;
#pragma unroll
  for (int i = 0; i < 8; ++i) o[i] = f2bf((bf2f(a[i]) + bf2f(b[i])) * rl);
  *(bf16x8*)(pO0 + i8) = o;
}

// K4: out = [attn|cb] @ [Wa|Wo]^T (R9, control).
template <typename TO>
__device__ __forceinline__ void out_body(
    const short* __restrict__ attn, const short* __restrict__ cb,
    const short* __restrict__ wb, TO* __restrict__ out) {
  __shared__ __align__(16) short As[128 * 64];
  __shared__ __align__(16) short Bs[64 * 64];
  const int t = threadIdx.x;
  const int wave = t >> 6, lane = t & 63;
  const int row = lane & 15, quad = lane >> 4;
  const int bn = blockIdx.x & 7;
  const int bm = blockIdx.x >> 3;
  const int m0 = bm * 128, n0 = bn * 64;
  const int wm = wave & 1, wn = wave >> 1;
  const int lrow = lane >> 3, lch = lane & 7;

  f32x4 acc[4][2];
#pragma unroll
  for (int mi = 0; mi < 4; ++mi)
#pragma unroll
    for (int ni = 0; ni < 2; ++ni)
#pragma unroll
      for (int r = 0; r < 4; ++r) acc[mi][ni][r] = 0.0f;

  const short* Wa = wb + 4 * kWElems;
  const short* Wo = wb + 5 * kWElems;

  for (int k0 = 0; k0 < 1024; k0 += 64) {
    const short* Asrc = (k0 < 512) ? attn : cb;
    const short* Bsrc = (k0 < 512) ? Wa : Wo;
    const int ka = k0 & 511;
#pragma unroll
    for (int p = 0; p < 4; ++p) {
      const int m = wave * 32 + p * 8 + lrow;
      const int kch = lch ^ (m & 7);
      gload_lds16(Asrc + (size_t)(m0 + m) * kC + ka + kch * 8,
                  &As[(wave * 32 + p * 8) * 64]);
    }
#pragma unroll
    for (int p = 0; p < 2; ++p) {
      const int n = wave * 16 + p * 8 + lrow;
      const int kch = lch ^ (n & 7);
      gload_lds16(Bsrc + (size_t)(n0 + n) * kC + ka + kch * 8,
                  &Bs[(wave * 16 + p * 8) * 64]);
    }
    __syncthreads();

#pragma unroll
    for (int kk2 = 0; kk2 < 2; ++kk2) {
      bf16x8 af[4], bfr[2];
#pragma unroll
      for (int mi = 0; mi < 4; ++mi) {
        const int m = wm * 64 + mi * 16 + row;
        const int ch = (kk2 * 4 + quad) ^ (m & 7);
        af[mi] = *(const bf16x8*)(&As[m * 64 + ch * 8]);
      }
#pragma unroll
      for (int ni = 0; ni < 2; ++ni) {
        const int n = wn * 32 + ni * 16 + row;
        const int ch = (kk2 * 4 + quad) ^ (n & 7);
        bfr[ni] = *(const bf16x8*)(&Bs[n * 64 + ch * 8]);
      }
#pragma unroll
      for (int mi = 0; mi < 4; ++mi)
#pragma unroll
        for (int ni = 0; ni < 2; ++ni)
          acc[mi][ni] = __builtin_amdgcn_mfma_f32_16x16x32_bf16(
              af[mi], bfr[ni], acc[mi][ni], 0, 0, 0);
    }
    __syncthreads();
  }

#pragma unroll
  for (int mi = 0; mi < 4; ++mi)
#pragma unroll
    for (int ni = 0; ni < 2; ++ni)
#pragma unroll
      for (int r = 0; r < 4; ++r) {
        const int gm = m0 + wm * 64 + mi * 16 + quad * 4 + r;
        const int gc = n0 + wn * 32 + ni * 16 + row;
        stf(out + (size_t)gm * kC + gc, acc[mi][ni][r]);
      }
}

__global__ __launch_bounds__(256, 4) void out_gemm(
    const short* __restrict__ attn, const short* __restrict__ cb,
    const short* __restrict__ wb, const int* __restrict__ flag, void* out) {
  if (*flag)
    out_body<short>(attn, cb, wb, (short*)out);
  else
    out_body<float>(attn, cb, wb, (float*)out);
}

extern "C" void kernel_launch(void* const* d_in, const int* in_sizes, int n_in,
                              void* d_out, int out_size, void* d_ws, size_t ws_size,
                              hipStream_t stream) {
  const void* x   = d_in[0];
  const void* Wq  = d_in[1];
  const void* Wk  = d_in[2];
  const void* Wv  = d_in[3];
  const void* Wa  = d_in[4];
  const void* Wc  = d_in[5];
  const void* dwk = d_in[6];
  const void* dwb = d_in[7];
  const void* Wco = d_in[8];

  short* ws = (short*)d_ws;
  const size_t E = (size_t)kBN * kC;
  int*   flag = (int*)ws;
  short* wb   = ws + 256;
  short* q    = wb + kWAll + kWExtra;
  short* k    = q + E;
  short* vT   = k + E;
  short* ci   = vT + E;
  short* cb   = ci + E;
  short* attn = ci;   // attn/partial0 overwrites ci (consumed by dwconv first)
  short* xb   = cb;   // consumed by proj_gemm before dwconv writes cb
  float* pl   = (float*)(cb + E);          // 2*16*4096 f32 = 512 KB
  short* pO1  = (short*)(pl) + 262144;     // 8.4 MB partial (split half 1)

  const size_t needS2 = ((size_t)(pO1 + E) - (size_t)ws);
  const int S = (ws_size >= needS2) ? 2 : 1;

  detect_dtype<<<1, 64, 0, stream>>>((const unsigned*)x, flag);
  const int cvt_threads = kW8 + kWExtra + kX8;
  convert_all<<<(cvt_threads + 255) / 256, 256, 0, stream>>>(
      Wq, Wk, Wv, Wc, Wa, Wco, dwk, dwb, x, flag, wb, xb);
  proj_gemm<<<1024, 256, 0, stream>>>(xb, wb, q, k, vT, ci);
  dwconv<<<(kBN * kC) / (256 * 8), 256, 0, stream>>>(ci, wb, cb);
  attn_flash<<<S * 256, 256, 0, stream>>>(q, k, vT, attn, pO1, pl, S);
  if (S == 2)
    attn_combine<<<(int)(E / 8 / 256), 256, 0, stream>>>(attn, pO1, pl);
  out_gemm<<<512, 256, 0, stream>>>(attn, cb, wb, flag, d_out);
}